// Round 1
// baseline (1421.594 us; speedup 1.0000x reference)
//
#include <hip/hip_runtime.h>

// GATConv with edge features, MI355X. Round 3: f16 MFMA for the edge GEMM.
//
// R2 post-mortem: edge_kernel (645us) not pipe-bound (HBM 21%, VALU 38%, conflicts 0).
// VALU time 0.38*645 ~= 248us ~= the theoretical issue time of the 4096 v_fmac_f32
// per thread -> the fp32 vector GEMM is the floor AND it starves latency hiding.
// Fix: compute m = edge_feat @ W_bot on the matrix cores (f16 inputs, fp32 accum).
//   - W fragments pre-arranged per-lane once (prep_w_kernel) -> conflict-free LDS reads
//   - edge rows staged as f16 with XOR swizzle (G4): byte ^= (row&7)<<4
//   - k-order uses kappa(g,j)=g*8+j for BOTH A and B frags -> correct for any HW k-map
//   - C/D layout (verified): col=lane&15, row=(lane>>4)*4+reg
//   - acc transposed through LDS back to [64 edges][128 ch] f32, then the R2
//     run-compressed epilogue runs VERBATIM.
//
// Algebra unchanged: m = src_proj[src] + edge_feat @ W_bot
//   rst = (sum_e exp(leaky(m+nh[dst])) * m) / (sum_e exp(leaky(m+nh[dst]))) + bias
// (max-free softmax: scores are O(12), exp fits fp32)

#define F 128      // F_IN
#define C 128      // H*D
#define NEG 0.2f
#define NN 50000
#define EE 800000

typedef _Float16 half8 __attribute__((ext_vector_type(8)));
typedef float f32x4 __attribute__((ext_vector_type(4)));

__device__ __forceinline__ void fma4(float4& a, float s, const float4 w) {
    a.x += s * w.x; a.y += s * w.y; a.z += s * w.z; a.w += s * w.w;
}

// ---------------- node projection: out[n][j] = sum_k in[n][k] * W[k][j]
// grid = (N/8, 2), block = 256.  y==0: src_feat@W_src_top -> src_proj ; y==1: dst_feat@W_dst -> nh
__global__ __launch_bounds__(256) void node_proj_kernel(
    const float* __restrict__ src_feat, const float* __restrict__ dst_feat,
    const float* __restrict__ W_src, const float* __restrict__ W_dst,
    float* __restrict__ src_proj, float* __restrict__ nh)
{
    const float* in; const float* W; float* out;
    if (blockIdx.y == 0) { in = src_feat; W = W_src; out = src_proj; }
    else                 { in = dst_feat; W = W_dst; out = nh; }

    __shared__ float4 xs[8 * 32];   // 8 rows x 128 floats
    const int t  = threadIdx.x;
    const int nb = blockIdx.x * 8;

    {
        int row = t >> 5, col = t & 31;
        xs[t] = ((const float4*)(in + (size_t)(nb + row) * F))[col];
    }
    __syncthreads();

    const int jq = t & 31;
    const int ng = t >> 5;
    float4 acc = make_float4(0.f, 0.f, 0.f, 0.f);
    const float4* W4 = (const float4*)W;

    #pragma unroll 4
    for (int k4 = 0; k4 < 32; ++k4) {
        float4 xv = xs[ng * 32 + k4];
        float4 w0 = W4[(4 * k4 + 0) * 32 + jq];
        float4 w1 = W4[(4 * k4 + 1) * 32 + jq];
        float4 w2 = W4[(4 * k4 + 2) * 32 + jq];
        float4 w3 = W4[(4 * k4 + 3) * 32 + jq];
        fma4(acc, xv.x, w0); fma4(acc, xv.y, w1);
        fma4(acc, xv.z, w2); fma4(acc, xv.w, w3);
    }
    ((float4*)(out + (size_t)(nb + ng) * C))[jq] = acc;
}

// ---------------- sort-by-dst machinery ----------------
__global__ __launch_bounds__(256) void hist_kernel(
    const int* __restrict__ dst_idx, int* __restrict__ deg)
{
    int e = blockIdx.x * 256 + threadIdx.x;
    if (e < EE) atomicAdd(&deg[dst_idx[e]], 1);
}

// exclusive prefix sum of deg[NN] -> cursor[NN]; single block of 1024 threads
__global__ __launch_bounds__(1024) void scan_kernel(
    const int* __restrict__ deg, int* __restrict__ cursor)
{
    __shared__ int ssum[1024];
    const int t = threadIdx.x;
    const int chunk = (NN + 1023) / 1024;   // 49
    int lo = t * chunk, hi = lo + chunk; if (hi > NN) hi = NN; if (lo > NN) lo = NN;
    int s = 0;
    for (int i = lo; i < hi; ++i) s += deg[i];
    ssum[t] = s;
    __syncthreads();
    for (int d = 1; d < 1024; d <<= 1) {
        int v = (t >= d) ? ssum[t - d] : 0;
        __syncthreads();
        ssum[t] += v;
        __syncthreads();
    }
    int run = ssum[t] - s;   // exclusive base
    for (int i = lo; i < hi; ++i) { cursor[i] = run; run += deg[i]; }
}

__global__ __launch_bounds__(256) void scatter_kernel(
    const int* __restrict__ dst_idx, int* __restrict__ cursor, int* __restrict__ elist)
{
    int e = blockIdx.x * 256 + threadIdx.x;
    if (e < EE) {
        int p = atomicAdd(&cursor[dst_idx[e]], 1);
        elist[p] = e;
    }
}

// ---------------- W_bot -> pre-arranged per-lane f16 B-fragments
// bfrag[((ct*4+ks)*64 + lane)*8 + j] = (f16) W_bot[k = ks*32 + (lane>>4)*8 + j][ct*16 + (lane&15)]
// Every wave reads its b-frag at lane-contiguous 16B -> conflict-free ds_read_b128.
__global__ __launch_bounds__(256) void prep_w_kernel(
    const float* __restrict__ W_src, _Float16* __restrict__ bfrag)
{
    int i = blockIdx.x * 256 + threadIdx.x;   // 0..16383, grid 64
    int j  = i & 7;
    int lw = (i >> 3) & 63;
    int ks = (i >> 9) & 3;
    int ct = i >> 11;
    int k  = ks * 32 + (lw >> 4) * 8 + j;
    int ch = ct * 16 + (lw & 15);
    bfrag[i] = (_Float16)W_src[(size_t)(128 + k) * 128 + ch];
}

// ---------------- edge pass over SORTED edges: f16 MFMA GEMM + gather + exp + run-compressed atomics
// grid = E/64, block = 256 (4 waves). Tile: 64 edges x 128 channels.
// Wave w: edges w*16..w*16+15 x all 128 ch = 8 MFMA col-tiles, K-loop 4 x K=32.
__global__ __launch_bounds__(256) void edge_kernel(
    const float* __restrict__ edge_feat, const _Float16* __restrict__ bfrag,
    const float* __restrict__ src_proj, const float* __restrict__ nh,
    const int* __restrict__ src_idx, const int* __restrict__ dst_idx,
    const int* __restrict__ elist,
    float* __restrict__ num, float* __restrict__ den)
{
    // A (f16 edge rows, swizzled) 16KB @ [0,16384) ; B frags 32KB @ [16384,49152)
    // m_lds (f32 [64][128]) 32KB @ [0,32768) -- reuses A+B after the MFMA barrier
    __shared__ __align__(16) unsigned char smem[49152];
    __shared__ int sidx[64];
    __shared__ int didx[64];
    __shared__ int es[64];

    const int t  = threadIdx.x;
    const int eb = blockIdx.x * 64;

    if (t < 64) {
        int e = elist[eb + t];
        es[t] = e;
        sidx[t] = src_idx[e];
        didx[t] = dst_idx[e];
    }
    __syncthreads();

    // stage B fragments: 32KB, lane-contiguous (L2-hot, shared by all blocks)
    {
        const float4* bg = (const float4*)bfrag;
        float4* bl = (float4*)(smem + 16384);
        #pragma unroll
        for (int i = 0; i < 8; ++i) bl[i * 256 + t] = bg[i * 256 + t];
    }

    // stage A: 64 edge rows fp32 -> f16, XOR-swizzled 16B chunks (byte ^= (row&7)<<4)
    #pragma unroll
    for (int i = 0; i < 4; ++i) {
        int flat = t + i * 256;          // 0..1023 = 64 rows x 16 chunks
        int r = flat >> 4, c = flat & 15;
        const float4* row = (const float4*)(edge_feat + (size_t)es[r] * F);
        float4 f0 = row[2 * c], f1 = row[2 * c + 1];
        half8 h;
        h[0] = (_Float16)f0.x; h[1] = (_Float16)f0.y;
        h[2] = (_Float16)f0.z; h[3] = (_Float16)f0.w;
        h[4] = (_Float16)f1.x; h[5] = (_Float16)f1.y;
        h[6] = (_Float16)f1.z; h[7] = (_Float16)f1.w;
        *(half8*)(smem + (r << 8) + ((c ^ (r & 7)) << 4)) = h;
    }
    __syncthreads();

    // MFMA: D[edge][ch], C/D map col=lane&15 (ch), row=(lane>>4)*4+reg (edge)
    const int l  = t & 63;
    const int w  = t >> 6;      // wave id = edge tile
    const int er = l & 15;      // A row / D col index
    const int g  = l >> 4;      // k-group
    f32x4 acc[8];
    {
        f32x4 z = {0.f, 0.f, 0.f, 0.f};
        #pragma unroll
        for (int ct = 0; ct < 8; ++ct) acc[ct] = z;
    }
    #pragma unroll
    for (int ks = 0; ks < 4; ++ks) {
        // kappa(g,j) = g*8+j for both operands -> k-map-invariant correctness
        half8 a = *(const half8*)(smem + ((w * 16 + er) << 8)
                                       + ((((ks << 2) + g) ^ (er & 7)) << 4));
        #pragma unroll
        for (int ct = 0; ct < 8; ++ct) {
            half8 b = *(const half8*)(smem + 16384 + ((((ct << 2) + ks) << 6) + l) * 16);
            acc[ct] = __builtin_amdgcn_mfma_f32_16x16x32_f16(a, b, acc[ct], 0, 0, 0);
        }
    }
    __syncthreads();   // all waves done reading A/B before overwrite

    // transpose acc -> m_lds[64 edges][128 ch] f32
    float* m_lds = (float*)smem;
    #pragma unroll
    for (int ct = 0; ct < 8; ++ct) {
        #pragma unroll
        for (int rg = 0; rg < 4; ++rg) {
            m_lds[(w * 16 + g * 4 + rg) * 128 + ct * 16 + er] = acc[ct][rg];
        }
    }
    __syncthreads();

    // epilogue (verbatim R2): edges sorted by dst -> run-compressed atomics
    const int jq = t & 31;   // channel quad: j0 = 4*jq
    const int eg = t >> 5;   // edge group 0..7 -> edges eg*8 .. eg*8+7

    int cur = didx[eg * 8];
    float4 nv = ((const float4*)(nh + (size_t)cur * C))[jq];
    float4 nacc = make_float4(0.f, 0.f, 0.f, 0.f);
    float4 dacc = make_float4(0.f, 0.f, 0.f, 0.f);

    #pragma unroll
    for (int i = 0; i < 8; ++i) {
        int el = eg * 8 + i;
        int d  = didx[el];
        if (d != cur) {
            float* np = num + (size_t)cur * C + jq * 4;
            float* dp = den + (size_t)cur * C + jq * 4;
            atomicAdd(np + 0, nacc.x); atomicAdd(np + 1, nacc.y);
            atomicAdd(np + 2, nacc.z); atomicAdd(np + 3, nacc.w);
            atomicAdd(dp + 0, dacc.x); atomicAdd(dp + 1, dacc.y);
            atomicAdd(dp + 2, dacc.z); atomicAdd(dp + 3, dacc.w);
            nacc = make_float4(0.f, 0.f, 0.f, 0.f);
            dacc = make_float4(0.f, 0.f, 0.f, 0.f);
            cur = d;
            nv = ((const float4*)(nh + (size_t)d * C))[jq];
        }
        float4 mi = *(const float4*)(m_lds + el * 128 + jq * 4);
        float4 sp = ((const float4*)(src_proj + (size_t)sidx[el] * C))[jq];

        float m0 = mi.x + sp.x, m1 = mi.y + sp.y;
        float m2 = mi.z + sp.z, m3 = mi.w + sp.w;

        float s0 = m0 + nv.x, s1 = m1 + nv.y, s2 = m2 + nv.z, s3 = m3 + nv.w;
        s0 = s0 > 0.f ? s0 : NEG * s0;
        s1 = s1 > 0.f ? s1 : NEG * s1;
        s2 = s2 > 0.f ? s2 : NEG * s2;
        s3 = s3 > 0.f ? s3 : NEG * s3;

        float e0 = __expf(s0), e1 = __expf(s1), e2 = __expf(s2), e3 = __expf(s3);

        nacc.x += e0 * m0; nacc.y += e1 * m1; nacc.z += e2 * m2; nacc.w += e3 * m3;
        dacc.x += e0;      dacc.y += e1;      dacc.z += e2;      dacc.w += e3;
    }
    {
        float* np = num + (size_t)cur * C + jq * 4;
        float* dp = den + (size_t)cur * C + jq * 4;
        atomicAdd(np + 0, nacc.x); atomicAdd(np + 1, nacc.y);
        atomicAdd(np + 2, nacc.z); atomicAdd(np + 3, nacc.w);
        atomicAdd(dp + 0, dacc.x); atomicAdd(dp + 1, dacc.y);
        atomicAdd(dp + 2, dacc.z); atomicAdd(dp + 3, dacc.w);
    }
}

// ---------------- finalize: out = num/den + bias  (den==0 -> bias, matches empty segment)
__global__ __launch_bounds__(256) void finalize_kernel(
    const float* __restrict__ num, const float* __restrict__ den,
    const float* __restrict__ bias, float* __restrict__ out)
{
    int i = blockIdx.x * 256 + threadIdx.x;      // float4 index
    float4 n = ((const float4*)num)[i];
    float4 d = ((const float4*)den)[i];
    float4 b = ((const float4*)bias)[i & 31];
    float4 r;
    r.x = (d.x != 0.f ? n.x / d.x : 0.f) + b.x;
    r.y = (d.y != 0.f ? n.y / d.y : 0.f) + b.y;
    r.z = (d.z != 0.f ? n.z / d.z : 0.f) + b.z;
    r.w = (d.w != 0.f ? n.w / d.w : 0.f) + b.w;
    ((float4*)out)[i] = r;
}

extern "C" void kernel_launch(void* const* d_in, const int* in_sizes, int n_in,
                              void* d_out, int out_size, void* d_ws, size_t ws_size,
                              hipStream_t stream) {
    const float* src_feat  = (const float*)d_in[0];
    const float* dst_feat  = (const float*)d_in[1];
    const float* edge_feat = (const float*)d_in[2];
    const float* W_src     = (const float*)d_in[3];   // [256][128]
    const float* W_dst     = (const float*)d_in[4];   // [128][128]
    const float* bias      = (const float*)d_in[5];   // [128]
    const int*   src_idx   = (const int*)d_in[6];
    const int*   dst_idx   = (const int*)d_in[7];
    float* out = (float*)d_out;                       // [50000][128] -> doubles as num accumulator

    const size_t NODEF = (size_t)NN * C;              // 6.4M floats

    float* ws       = (float*)d_ws;
    float* src_proj = ws;                             // 6.4M floats
    float* nh       = ws + NODEF;                     // 6.4M floats
    float* den      = ws + 2 * NODEF;                 // 6.4M floats
    int*   deg      = (int*)(ws + 3 * NODEF);         // NN ints
    int*   cursor   = deg + NN;                       // NN ints
    int*   elist    = cursor + NN;                    // EE ints
    _Float16* bfrag = (_Float16*)(elist + EE);        // 16384 f16 = 32KB (16B-aligned)

    float* num = out;  // accumulate numerator directly in d_out, finalize in place

    hipMemsetAsync(num, 0, NODEF * sizeof(float), stream);
    hipMemsetAsync(den, 0, NODEF * sizeof(float), stream);
    hipMemsetAsync(deg, 0, NN * sizeof(int), stream);

    // build dst-sorted edge list
    hist_kernel<<<(EE + 255) / 256, 256, 0, stream>>>(dst_idx, deg);
    scan_kernel<<<1, 1024, 0, stream>>>(deg, cursor);
    scatter_kernel<<<(EE + 255) / 256, 256, 0, stream>>>(dst_idx, cursor, elist);

    // W_bot -> per-lane f16 MFMA fragments (once; L2-resident for the edge pass)
    prep_w_kernel<<<64, 256, 0, stream>>>(W_src, bfrag);

    // node projections (independent of the sort)
    node_proj_kernel<<<dim3(NN / 8, 2), 256, 0, stream>>>(
        src_feat, dst_feat, W_src, W_dst, src_proj, nh);

    // sorted edge pass (f16 MFMA GEMM + fused softmax-aggregate epilogue)
    edge_kernel<<<EE / 64, 256, 0, stream>>>(
        edge_feat, bfrag, src_proj, nh, src_idx, dst_idx, elist, num, den);

    finalize_kernel<<<NODEF / 4 / 256, 256, 0, stream>>>(num, den, bias, out);
}